// Round 6
// baseline (531.333 us; speedup 1.0000x reference)
//
#include <hip/hip_runtime.h>
#include <hip/hip_bf16.h>
#include <math.h>

#define DF 64

typedef __attribute__((ext_vector_type(8))) short short8v;   // 8 bf16 = 4 VGPRs
typedef __attribute__((ext_vector_type(4))) float f32x4;

__global__ __launch_bounds__(256) void zero_int_kernel(int* __restrict__ p, int n) {
  int i = blockIdx.x * 256 + threadIdx.x;
  if (i < n) p[i] = 0;
}

__global__ __launch_bounds__(256) void deg_kernel(const int* __restrict__ dst,
                                                  int* __restrict__ deg, int e) {
  int i = blockIdx.x * 256 + threadIdx.x;
  if (i < e) atomicAdd(&deg[dst[i]], 1);
}

// hierarchical scan, stage 1: per-block (1024) exclusive scan + block sum
__global__ __launch_bounds__(1024) void scan_block_kernel(const int* __restrict__ deg,
                                                          int* __restrict__ part,
                                                          int* __restrict__ bsum, int n) {
  __shared__ int a[1024];
  const int t = threadIdx.x;
  const int i = blockIdx.x * 1024 + t;
  int v = (i < n) ? deg[i] : 0;
  a[t] = v;
  __syncthreads();
  for (int off = 1; off < 1024; off <<= 1) {
    int addv = (t >= off) ? a[t - off] : 0;
    __syncthreads();
    a[t] += addv;
    __syncthreads();
  }
  if (i < n) part[i] = a[t] - v;
  if (t == 1023) bsum[blockIdx.x] = a[1023];
}

// stage 2: single-wave exclusive scan of <=64 block sums; writes rowp[n]=total
__global__ __launch_bounds__(64) void scan_sums_kernel(const int* __restrict__ bsum,
                                                       int* __restrict__ boff,
                                                       int* __restrict__ rowp_last,
                                                       int nb) {
  const int t = threadIdx.x;
  int v = (t < nb) ? bsum[t] : 0;
  const int orig = v;
  for (int off = 1; off < 64; off <<= 1) {
    int u = __shfl_up(v, off);
    if (t >= off) v += u;
  }
  if (t < nb) boff[t] = v - orig;
  if (t == nb - 1) rowp_last[0] = v;
}

// stage 3: add block offsets
__global__ __launch_bounds__(256) void scan_apply_kernel(const int* __restrict__ part,
                                                         const int* __restrict__ boff,
                                                         int* __restrict__ rowp,
                                                         int* __restrict__ curs, int n) {
  int i = blockIdx.x * 256 + threadIdx.x;
  if (i < n) {
    int v = part[i] + boff[i >> 10];
    rowp[i] = v;
    curs[i] = v;
  }
}

__global__ __launch_bounds__(256) void fill_kernel(const int* __restrict__ src,
                                                   const int* __restrict__ dst,
                                                   int* __restrict__ curs,
                                                   int* __restrict__ csr, int e) {
  int i = blockIdx.x * 256 + threadIdx.x;
  if (i < e) {
    int p = atomicAdd(&curs[dst[i]], 1);
    csr[p] = src[i];
  }
}

// Combined GEMM weights in FRAGMENT ORDER so gru B-loads are coalesced 1KB reads.
// Logical matrix WB[c][k], c=0..255, k=0..127:
//   c in [0,64):    r-gate:  k<64 -> Wc_r[k][f],  k>=64 -> w_hh[f][k-64]
//   c in [64,128):  z-gate:  k<64 -> Wc_z[k][f],  k>=64 -> w_hh[64+f][k-64]
//   c in [128,192): i_n:     k<64 -> Wc_n[k][f],  k>=64 -> 0
//   c in [192,256): h_n:     k<64 -> 0,           k>=64 -> w_hh[128+f][k-64]
// Wc_g[k][f] = sum_t W[l][k][t] * w_ih[g*64+f][t]
// Storage: WBf[l][jb][chq][row][t]  with c = jb*16+row, k = chq*8+t.
__global__ __launch_bounds__(256) void wb_kernel(const float* __restrict__ W,
                                                 const float* __restrict__ wih,
                                                 const float* __restrict__ whh,
                                                 __hip_bfloat16* __restrict__ WBf,
                                                 int total) {
  int idx = blockIdx.x * 256 + threadIdx.x;
  if (idx >= total) return;
  int t   = idx & 7;
  int row = (idx >> 3) & 15;
  int chq = (idx >> 7) & 15;
  int jb  = (idx >> 11) & 15;
  int l   = idx >> 15;
  int k = chq * 8 + t;
  int c = jb * 16 + row;
  int g = c >> 6;   // 0:r 1:z 2:i_n 3:h_n
  int f = c & 63;
  float v = 0.f;
  if (k < 64) {
    if (g != 3) {
      int crow = (g == 0) ? f : (g == 1) ? (64 + f) : (128 + f);
      const float* wr = W + ((size_t)l * 64 + k) * 64;
      const float* ir = wih + (size_t)crow * 64;
      float s = 0.f;
#pragma unroll
      for (int t2 = 0; t2 < 64; ++t2) s = fmaf(wr[t2], ir[t2], s);
      v = s;
    }
  } else {
    if (g != 2) {
      int crow = (g == 0) ? f : (g == 1) ? (64 + f) : (128 + f);
      v = whh[(size_t)crow * 64 + (k - 64)];
    }
  }
  WBf[idx] = __float2bfloat16(v);
}

// split fp32 x -> bf16 feature-half arrays hA (f 0..31), hB (f 32..63)
__global__ __launch_bounds__(256) void cvt_kernel(const float* __restrict__ x,
                                                  __hip_bfloat16* __restrict__ hA,
                                                  __hip_bfloat16* __restrict__ hB, int n) {
  int i = blockIdx.x * 256 + threadIdx.x;
  if (i >= n) return;
  int f = i & 63, node = i >> 6;
  __hip_bfloat16 v = __float2bfloat16(x[i]);
  if (f < 32) hA[(size_t)node * 32 + f] = v;
  else        hB[(size_t)node * 32 + (f - 32)] = v;
}

// one wave per node, one 32-feature half per pass (working set 3.2MB -> per-XCD L2).
// lanes 0..31: even-indexed edges; lanes 32..63: odd-indexed edges; combine via shfl.
__global__ __launch_bounds__(256) void gather_kernel(const __hip_bfloat16* __restrict__ hX,
                                                     const int* __restrict__ rowp,
                                                     const int* __restrict__ csr,
                                                     __hip_bfloat16* __restrict__ segX,
                                                     int n) {
  int w = (int)((blockIdx.x * 256 + threadIdx.x) >> 6);
  if (w >= n) return;
  const int lane = threadIdx.x & 63;
  const int f = lane & 31;
  const int half = lane >> 5;
  const int beg = rowp[w], end = rowp[w + 1];
  float acc = 0.f, acc2 = 0.f;
  int e = beg + half;
  for (; e + 2 < end; e += 4) {
    acc  += __bfloat162float(hX[(size_t)csr[e] * 32 + f]);
    acc2 += __bfloat162float(hX[(size_t)csr[e + 2] * 32 + f]);
  }
  if (e < end) acc += __bfloat162float(hX[(size_t)csr[e] * 32 + f]);
  acc += acc2;
  acc += __shfl_xor(acc, 32);
  if (half == 0) segX[(size_t)w * 32 + f] = __float2bfloat16(acc);
}

#define MFMA(acc, a, b) acc = __builtin_amdgcn_mfma_f32_16x16x32_bf16(a, b, acc, 0, 0, 0)

// LDS-free fused GRU. Each wave: 2 tiles of 16 nodes; B-fragments register-hoisted
// per j-block and reused across tiles; A-fragments hoisted across all j.
__global__ __launch_bounds__(256) void gru_mfma_kernel(
    const __hip_bfloat16* __restrict__ segA, const __hip_bfloat16* __restrict__ segB,
    __hip_bfloat16* __restrict__ hA, __hip_bfloat16* __restrict__ hB,
    const float* __restrict__ bih, const float* __restrict__ bhh,
    const __hip_bfloat16* __restrict__ WBl,  // layer's fragment-ordered weights
    float* __restrict__ out, int writeOut, int n) {
  const int lane = threadIdx.x & 63;
  const int wid = threadIdx.x >> 6;
  const int row = lane & 15;     // A-row (node within 16) == B/C col (feature within 16)
  const int quad = lane >> 4;    // 0..3
  const int base = (blockIdx.x * 4 + wid) * 32;
  if (base >= n) return;
  const bool v1 = (base + 16) < n;   // tile 1 exists (N%16==0 so tile0 always full)

  const size_t ro0 = (size_t)(base + row) * 32 + quad * 8;
  const size_t ro1 = (size_t)(base + 16 + row) * 32 + quad * 8;
  const short8v a0_0 = *(const short8v*)(segA + ro0);
  const short8v a1_0 = *(const short8v*)(segB + ro0);
  const short8v a2_0 = *(const short8v*)(hA + ro0);
  const short8v a3_0 = *(const short8v*)(hB + ro0);
  const short8v a0_1 = v1 ? *(const short8v*)(segA + ro1) : a0_0;
  const short8v a1_1 = v1 ? *(const short8v*)(segB + ro1) : a1_0;
  const short8v a2_1 = v1 ? *(const short8v*)(hA + ro1) : a2_0;
  const short8v a3_1 = v1 ? *(const short8v*)(hB + ro1) : a3_0;

#pragma unroll
  for (int j = 0; j < 4; ++j) {
    // B fragment (jb, chunk-base cb): 16B/lane, wave reads 1KB contiguous
    const __hip_bfloat16* Wj = WBl;
    auto LDB = [&](int jb, int cb) {
      return *(const short8v*)(Wj + (((jb * 16 + cb + quad) * 16 + row) << 3));
    };
    const short8v bR0 = LDB(j, 0),      bR1 = LDB(j, 4),      bR2 = LDB(j, 8),      bR3 = LDB(j, 12);
    const short8v bZ0 = LDB(4 + j, 0),  bZ1 = LDB(4 + j, 4),  bZ2 = LDB(4 + j, 8),  bZ3 = LDB(4 + j, 12);
    const short8v bN0 = LDB(8 + j, 0),  bN1 = LDB(8 + j, 4);
    const short8v bH0 = LDB(12 + j, 8), bH1 = LDB(12 + j, 12);

    const int fr = j * 16 + row;
    const float bir = bih[fr], biz = bih[64 + fr], bin_ = bih[128 + fr];
    const float bhr = bhh[fr], bhz = bhh[64 + fr], bhn = bhh[128 + fr];
    __hip_bfloat16* hX = (j < 2) ? hA : hB;
    const int fo = ((j & 1) << 4) + row;

    auto tileCompute = [&](short8v A0, short8v A1, short8v A2, short8v A3, int nb) {
      f32x4 aR = {0.f, 0.f, 0.f, 0.f}, aZ = {0.f, 0.f, 0.f, 0.f};
      f32x4 aN = {0.f, 0.f, 0.f, 0.f}, aH = {0.f, 0.f, 0.f, 0.f};
      MFMA(aR, A0, bR0); MFMA(aR, A1, bR1); MFMA(aR, A2, bR2); MFMA(aR, A3, bR3);
      MFMA(aZ, A0, bZ0); MFMA(aZ, A1, bZ1); MFMA(aZ, A2, bZ2); MFMA(aZ, A3, bZ3);
      MFMA(aN, A0, bN0); MFMA(aN, A1, bN1);
      MFMA(aH, A2, bH0); MFMA(aH, A3, bH1);
#pragma unroll
      for (int e = 0; e < 4; ++e) {
        const int node = nb + quad * 4 + e;
        const float hprev = __bfloat162float(hX[(size_t)node * 32 + fo]);
        const float r = 1.f / (1.f + __expf(-(aR[e] + bir + bhr)));
        const float z = 1.f / (1.f + __expf(-(aZ[e] + biz + bhz)));
        const float nn = tanhf(aN[e] + bin_ + r * (aH[e] + bhn));
        const float ho = fmaf(z, hprev - nn, nn);
        hX[(size_t)node * 32 + fo] = __float2bfloat16(ho);
        if (writeOut) out[(size_t)node * DF + fr] = ho;
      }
    };
    tileCompute(a0_0, a1_0, a2_0, a3_0, base);
    if (v1) tileCompute(a0_1, a1_1, a2_1, a3_1, base + 16);
  }
}

extern "C" void kernel_launch(void* const* d_in, const int* in_sizes, int n_in,
                              void* d_out, int out_size, void* d_ws, size_t ws_size,
                              hipStream_t stream) {
  const float* x   = (const float*)d_in[0];
  const int*   ei  = (const int*)d_in[1];
  const float* wgt = (const float*)d_in[2];
  const float* wih = (const float*)d_in[3];
  const float* whh = (const float*)d_in[4];
  const float* bih = (const float*)d_in[5];
  const float* bhh = (const float*)d_in[6];
  float* out = (float*)d_out;

  const int N = in_sizes[0] / DF;
  const int E = in_sizes[1] / 2;
  const int L = in_sizes[2] / (DF * DF);

  const int* srcv = ei;
  const int* dstv = ei + E;

  __hip_bfloat16* hA   = (__hip_bfloat16*)d_ws;
  __hip_bfloat16* hB   = hA + (size_t)N * 32;
  __hip_bfloat16* segA = hB + (size_t)N * 32;
  __hip_bfloat16* segB = segA + (size_t)N * 32;
  __hip_bfloat16* WBf  = segB + (size_t)N * 32;
  int* deg  = (int*)(WBf + (size_t)L * 256 * 128);
  int* rowp = deg + N;
  int* curs = rowp + (N + 1);
  int* csr  = curs + N;
  int* part = csr + E;
  int* bsum = part + N;
  int* boff = bsum + 64;

  const int NB = (N + 1023) / 1024;  // 49 for N=50000 (must be <= 64)

  // CSR build (once per call; ws is re-poisoned every call)
  zero_int_kernel<<<(N + 255) / 256, 256, 0, stream>>>(deg, N);
  deg_kernel<<<(E + 255) / 256, 256, 0, stream>>>(dstv, deg, E);
  scan_block_kernel<<<NB, 1024, 0, stream>>>(deg, part, bsum, N);
  scan_sums_kernel<<<1, 64, 0, stream>>>(bsum, boff, rowp + N, NB);
  scan_apply_kernel<<<(N + 255) / 256, 256, 0, stream>>>(part, boff, rowp, curs, N);
  fill_kernel<<<(E + 255) / 256, 256, 0, stream>>>(srcv, dstv, curs, csr, E);

  // fragment-ordered bf16 weights + bf16 split copy of initial h
  wb_kernel<<<(L * 256 * 128 + 255) / 256, 256, 0, stream>>>(wgt, wih, whh, WBf,
                                                             L * 256 * 128);
  cvt_kernel<<<(N * DF + 255) / 256, 256, 0, stream>>>(x, hA, hB, N * DF);

  const int gatherGrid = (N * DF + 255) / 256;  // one wave per node
  const int gruGrid = (N + 127) / 128;          // 4 waves x 2 tiles of 16
  for (int i = 0; i < L; ++i) {
    gather_kernel<<<gatherGrid, 256, 0, stream>>>(hA, rowp, csr, segA, N);
    gather_kernel<<<gatherGrid, 256, 0, stream>>>(hB, rowp, csr, segB, N);
    gru_mfma_kernel<<<gruGrid, 256, 0, stream>>>(segA, segB, hA, hB, bih, bhh,
                                                 WBf + (size_t)i * 256 * 128, out,
                                                 (i == L - 1) ? 1 : 0, N);
  }
}

// Round 9
// 369.147 us; speedup vs baseline: 1.4394x; 1.4394x over previous
//
#include <hip/hip_runtime.h>
#include <hip/hip_bf16.h>
#include <math.h>

#define DF 64
#define NPB 128        // nodes per bucket (shift 7)
#define EPB 2048       // edges per block in bucket phases
#define DCAP 4608      // Phase-D per-bucket edge capacity (mean 2046, >50 sigma margin)

typedef __attribute__((ext_vector_type(8))) short short8v;   // 8 bf16 = 4 VGPRs
typedef __attribute__((ext_vector_type(4))) float f32x4;

__global__ __launch_bounds__(256) void zero_int_kernel(int* __restrict__ p, int n) {
  int i = blockIdx.x * 256 + threadIdx.x;
  if (i < n) p[i] = 0;
}

// Phase A: per-block LDS histogram of dst buckets -> global bucket counts
__global__ __launch_bounds__(256) void bkt_count_kernel(const int* __restrict__ dst,
                                                        int* __restrict__ bcount,
                                                        int e, int nbk) {
  __shared__ int cnt[512];
  for (int i = threadIdx.x; i < nbk; i += 256) cnt[i] = 0;
  __syncthreads();
  const int eb = blockIdx.x * EPB;
  const int ee = (eb + EPB < e) ? (eb + EPB) : e;
  for (int i = eb + threadIdx.x; i < ee; i += 256) atomicAdd(&cnt[dst[i] >> 7], 1);
  __syncthreads();
  for (int i = threadIdx.x; i < nbk; i += 256)
    if (cnt[i]) atomicAdd(&bcount[i], cnt[i]);
}

// Phase B: one-block exclusive scan of bucket counts (nbk <= 512); init cursors
__global__ __launch_bounds__(512) void bkt_scan_kernel(const int* __restrict__ bcount,
                                                       int* __restrict__ boff,
                                                       int* __restrict__ bcur,
                                                       int* __restrict__ rowp_last,
                                                       int e, int nbk) {
  __shared__ int a[512];
  const int t = threadIdx.x;
  int v = (t < nbk) ? bcount[t] : 0;
  a[t] = v;
  __syncthreads();
  for (int off = 1; off < 512; off <<= 1) {
    int add = (t >= off) ? a[t - off] : 0;
    __syncthreads();
    a[t] += add;
    __syncthreads();
  }
  int excl = a[t] - v;
  if (t < nbk) { boff[t] = excl; bcur[t] = excl; }
  if (t == nbk - 1) { boff[nbk] = excl + v; rowp_last[0] = e; }
}

// Phase C: bin edges into bucket segments as (src, dst&127) pairs.
// LDS ranking + one global reservation per (block,bucket) -> grouped burst writes
// (kills the 52MB cross-XCD write amplification of the old 4B-scatter fill).
__global__ __launch_bounds__(256) void bkt_fill_kernel(const int* __restrict__ src,
                                                       const int* __restrict__ dst,
                                                       int* __restrict__ bcur,
                                                       int2* __restrict__ bpairs,
                                                       int e, int nbk) {
  __shared__ int cnt[512];
  __shared__ int base[512];
  for (int i = threadIdx.x; i < nbk; i += 256) cnt[i] = 0;
  __syncthreads();
  const int eb = blockIdx.x * EPB;
  int s[8], d[8], r[8];
#pragma unroll
  for (int q = 0; q < 8; ++q) {
    int i = eb + q * 256 + threadIdx.x;
    bool ok = i < e;
    s[q] = ok ? src[i] : 0;
    d[q] = ok ? dst[i] : 0;
    r[q] = ok ? atomicAdd(&cnt[d[q] >> 7], 1) : 0;
  }
  __syncthreads();
  for (int i = threadIdx.x; i < nbk; i += 256)
    base[i] = cnt[i] ? atomicAdd(&bcur[i], cnt[i]) : 0;
  __syncthreads();
#pragma unroll
  for (int q = 0; q < 8; ++q) {
    int i = eb + q * 256 + threadIdx.x;
    if (i < e) {
      int b = d[q] >> 7;
      bpairs[base[b] + r[q]] = make_int2(s[q], d[q] & (NPB - 1));
    }
  }
}

// Phase D: one workgroup per bucket. Local hist -> scan -> LDS scatter;
// rowp and csr written fully coalesced.
__global__ __launch_bounds__(256) void bkt_csr_kernel(const int2* __restrict__ bpairs,
                                                      const int* __restrict__ boff,
                                                      int* __restrict__ rowp,
                                                      int* __restrict__ csr,
                                                      int n, int nbk) {
  __shared__ int cnt[NPB], cur[NPB], sa[NPB];
  __shared__ int lsrc[DCAP], ldst[DCAP], lcsr[DCAP];
  const int b = blockIdx.x;
  const int t = threadIdx.x;
  const int e0 = boff[b];
  int cnt_e = boff[b + 1] - e0;
  if (cnt_e > DCAP) cnt_e = DCAP;  // never triggers at this E/N; guards LDS OOB
  if (t < NPB) cnt[t] = 0;
  __syncthreads();
  for (int i = t; i < cnt_e; i += 256) {
    int2 p = bpairs[e0 + i];
    lsrc[i] = p.x;
    ldst[i] = p.y;
    atomicAdd(&cnt[p.y], 1);
  }
  __syncthreads();
  if (t < NPB) sa[t] = cnt[t];
  __syncthreads();
  for (int off = 1; off < NPB; off <<= 1) {
    int add = (t < NPB && t >= off) ? sa[t - off] : 0;
    __syncthreads();
    if (t < NPB) sa[t] += add;
    __syncthreads();
  }
  if (t < NPB) {
    int excl = sa[t] - cnt[t];
    cur[t] = excl;
    int node = b * NPB + t;
    if (node < n) rowp[node] = e0 + excl;
  }
  __syncthreads();
  for (int i = t; i < cnt_e; i += 256) {
    int p = atomicAdd(&cur[ldst[i]], 1);
    lcsr[p] = lsrc[i];
  }
  __syncthreads();
  for (int i = t; i < cnt_e; i += 256) csr[e0 + i] = lcsr[i];
}

// Combined GEMM weights, bf16, layout WB[l][c][k], c in 0..255, k in 0..127.
//   c in [0,64):    r-gate combined:  k<64 -> Wc_r[k][f],  k>=64 -> w_hh[f][k-64]
//   c in [64,128):  z-gate combined:  k<64 -> Wc_z[k][f],  k>=64 -> w_hh[64+f][k-64]
//   c in [128,192): i_n only:         k<64 -> Wc_n[k][f],  k>=64 -> 0
//   c in [192,256): h_n only:         k<64 -> 0,           k>=64 -> w_hh[128+f][k-64]
// where Wc_g[k][f] = sum_t W[l][k][t] * w_ih[g*64+f][t]
__global__ __launch_bounds__(256) void wb_kernel(const float* __restrict__ W,
                                                 const float* __restrict__ wih,
                                                 const float* __restrict__ whh,
                                                 __hip_bfloat16* __restrict__ WB,
                                                 int total) {
  int idx = blockIdx.x * 256 + threadIdx.x;
  if (idx >= total) return;
  int k = idx & 127;
  int c = (idx >> 7) & 255;
  int l = idx >> 15;
  int g = c >> 6;   // 0:r 1:z 2:i_n 3:h_n
  int f = c & 63;
  float v = 0.f;
  if (k < 64) {
    if (g != 3) {
      int crow = (g == 0) ? f : (g == 1) ? (64 + f) : (128 + f);
      const float* wr = W + ((size_t)l * 64 + k) * 64;
      const float* ir = wih + (size_t)crow * 64;
      float s = 0.f;
#pragma unroll
      for (int t2 = 0; t2 < 64; ++t2) s = fmaf(wr[t2], ir[t2], s);
      v = s;
    }
  } else {
    if (g != 2) {
      int crow = (g == 0) ? f : (g == 1) ? (64 + f) : (128 + f);
      v = whh[(size_t)crow * 64 + (k - 64)];
    }
  }
  WB[idx] = __float2bfloat16(v);
}

__global__ __launch_bounds__(256) void cvt_kernel(const float* __restrict__ x,
                                                  __hip_bfloat16* __restrict__ o, int n) {
  int i = blockIdx.x * 256 + threadIdx.x;
  if (i < n) o[i] = __float2bfloat16(x[i]);
}

// one wave per node: segHb[n][lane] = bf16( sum over incoming edges of hb[src][lane] )
__global__ __launch_bounds__(256) void gather_kernel(const __hip_bfloat16* __restrict__ hb,
                                                     const int* __restrict__ rowp,
                                                     const int* __restrict__ csr,
                                                     __hip_bfloat16* __restrict__ segHb,
                                                     int n) {
  int gw = (int)((blockIdx.x * 256 + threadIdx.x) >> 6);
  int lane = threadIdx.x & 63;
  if (gw >= n) return;
  int beg = rowp[gw], end = rowp[gw + 1];
  float acc = 0.f;
  int e = beg;
  for (; e + 4 <= end; e += 4) {
    int s0 = csr[e], s1 = csr[e + 1], s2 = csr[e + 2], s3 = csr[e + 3];
    float v0 = __bfloat162float(hb[(size_t)s0 * DF + lane]);
    float v1 = __bfloat162float(hb[(size_t)s1 * DF + lane]);
    float v2 = __bfloat162float(hb[(size_t)s2 * DF + lane]);
    float v3 = __bfloat162float(hb[(size_t)s3 * DF + lane]);
    acc += v0 + v1 + v2 + v3;
  }
  for (; e < end; ++e) acc += __bfloat162float(hb[(size_t)csr[e] * DF + lane]);
  segHb[(size_t)gw * DF + lane] = __float2bfloat16(acc);
}

// swizzled LDS B-fragment read: element block (c, chunk) of WB_l[c][k]
// byte addr = c*256 + ((chunk ^ (c&15)) * 16)   (chunk = 16B block index along k)
__device__ __forceinline__ short8v ldB(const char* sB, int c, int chunk) {
  return *(const short8v*)(sB + c * 256 + ((chunk ^ (c & 15)) * 16));
}

#define MFMA(acc, a, b) acc = __builtin_amdgcn_mfma_f32_16x16x32_bf16(a, b, acc, 0, 0, 0)

// Fused GRU step via MFMA (R4 structure, benched 422us total):
//   pre[N][256] = [segHb | hbf] (N x 128, bf16) @ WB (128 x 256, bf16)
//   r = sigmoid(pre[0:64]+bi_r+bh_r); z = sigmoid(pre[64:128]+bi_z+bh_z)
//   n = tanh(pre[128:192]+bi_n + r*(pre[192:256]+bh_n)); h' = n + z*(h-n)
__global__ __launch_bounds__(256, 2) void gru_mfma_kernel(
    const __hip_bfloat16* __restrict__ segHb, const float* __restrict__ hin,
    __hip_bfloat16* __restrict__ hbf,  // read (A k>=64) AND written in place (bf16 of h')
    const float* __restrict__ bih, const float* __restrict__ bhh,
    const __hip_bfloat16* __restrict__ WB, float* __restrict__ hout, int n) {
  __shared__ __hip_bfloat16 sB[256 * 128];  // 64 KiB, chunk-XOR swizzled
#pragma unroll
  for (int i = 0; i < 16; ++i) {
    int idx = i * 256 + threadIdx.x;
    int c = idx >> 4, ch = idx & 15;
    short8v v = *(const short8v*)(WB + (size_t)c * 128 + ch * 8);
    *(short8v*)((char*)sB + c * 256 + ((ch ^ (c & 15)) * 16)) = v;
  }
  __syncthreads();

  const char* sBc = (const char*)sB;
  const int lane = threadIdx.x & 63;
  const int wid = threadIdx.x >> 6;
  const int row = lane & 15;     // node within 16-group (A); col within 16 (B/C)
  const int quad = lane >> 4;    // 0..3
  const int ch0 = quad, ch1 = 4 + quad, ch2 = 8 + quad, ch3 = 12 + quad;

  float bi_r[4], bi_z[4], bi_n[4], bh_r[4], bh_z[4], bh_n[4];
#pragma unroll
  for (int j = 0; j < 4; ++j) {
    int f = j * 16 + row;
    bi_r[j] = bih[f]; bi_z[j] = bih[64 + f]; bi_n[j] = bih[128 + f];
    bh_r[j] = bhh[f]; bh_z[j] = bhh[64 + f]; bh_n[j] = bhh[128 + f];
  }

  for (int nb0 = blockIdx.x * 64; nb0 < n; nb0 += gridDim.x * 64) {
    const int nb = nb0 + wid * 16;
    if (nb >= n) continue;
    const short8v a0 = *(const short8v*)(segHb + (size_t)(nb + row) * DF + quad * 8);
    const short8v a1 = *(const short8v*)(segHb + (size_t)(nb + row) * DF + 32 + quad * 8);
    const short8v a2 = *(const short8v*)(hbf + (size_t)(nb + row) * DF + quad * 8);
    const short8v a3 = *(const short8v*)(hbf + (size_t)(nb + row) * DF + 32 + quad * 8);

    f32x4 accR[4], accZ[4], accN[4], accH[4];
#pragma unroll
    for (int j = 0; j < 4; ++j) {
      accR[j] = (f32x4){0.f, 0.f, 0.f, 0.f};
      accZ[j] = (f32x4){0.f, 0.f, 0.f, 0.f};
      accN[j] = (f32x4){0.f, 0.f, 0.f, 0.f};
      accH[j] = (f32x4){0.f, 0.f, 0.f, 0.f};
    }
    // B-fragment column is PER-LANE: c = block + row
#pragma unroll
    for (int j = 0; j < 4; ++j) {
      MFMA(accR[j], a0, ldB(sBc, j * 16 + row, ch0));
      MFMA(accR[j], a1, ldB(sBc, j * 16 + row, ch1));
      MFMA(accR[j], a2, ldB(sBc, j * 16 + row, ch2));
      MFMA(accR[j], a3, ldB(sBc, j * 16 + row, ch3));
      MFMA(accZ[j], a0, ldB(sBc, 64 + j * 16 + row, ch0));
      MFMA(accZ[j], a1, ldB(sBc, 64 + j * 16 + row, ch1));
      MFMA(accZ[j], a2, ldB(sBc, 64 + j * 16 + row, ch2));
      MFMA(accZ[j], a3, ldB(sBc, 64 + j * 16 + row, ch3));
      MFMA(accN[j], a0, ldB(sBc, 128 + j * 16 + row, ch0));
      MFMA(accN[j], a1, ldB(sBc, 128 + j * 16 + row, ch1));
      MFMA(accH[j], a2, ldB(sBc, 192 + j * 16 + row, ch2));
      MFMA(accH[j], a3, ldB(sBc, 192 + j * 16 + row, ch3));
    }
    // epilogue: C layout col(lane&15)=feature-within-16, out-row = quad*4 + e = node
#pragma unroll
    for (int j = 0; j < 4; ++j) {
#pragma unroll
      for (int e = 0; e < 4; ++e) {
        const int node = nb + quad * 4 + e;
        const int f = j * 16 + row;
        const float hprev = hin[(size_t)node * DF + f];
        const float r = 1.f / (1.f + __expf(-(accR[j][e] + bi_r[j] + bh_r[j])));
        const float z = 1.f / (1.f + __expf(-(accZ[j][e] + bi_z[j] + bh_z[j])));
        const float nn = tanhf(accN[j][e] + bi_n[j] + r * (accH[j][e] + bh_n[j]));
        const float ho = fmaf(z, hprev - nn, nn);
        hout[(size_t)node * DF + f] = ho;
        hbf[(size_t)node * DF + f] = __float2bfloat16(ho);
      }
    }
  }
}

extern "C" void kernel_launch(void* const* d_in, const int* in_sizes, int n_in,
                              void* d_out, int out_size, void* d_ws, size_t ws_size,
                              hipStream_t stream) {
  const float* x   = (const float*)d_in[0];
  const int*   ei  = (const int*)d_in[1];
  const float* wgt = (const float*)d_in[2];
  const float* wih = (const float*)d_in[3];
  const float* whh = (const float*)d_in[4];
  const float* bih = (const float*)d_in[5];
  const float* bhh = (const float*)d_in[6];
  float* out = (float*)d_out;

  const int N = in_sizes[0] / DF;
  const int E = in_sizes[1] / 2;
  const int L = in_sizes[2] / (DF * DF);

  const int* srcv = ei;
  const int* dstv = ei + E;

  float* hA = (float*)d_ws;
  float* hB = hA + (size_t)N * DF;
  __hip_bfloat16* segHb = (__hip_bfloat16*)(hB + (size_t)N * DF);
  __hip_bfloat16* hbf   = segHb + (size_t)N * DF;
  __hip_bfloat16* WB    = hbf + (size_t)N * DF;
  int* rowp   = (int*)(WB + (size_t)L * 256 * 128);
  int* csr    = rowp + (N + 1);
  int* bcount = csr + E;
  int* boff   = bcount + 512;
  int* bcur   = boff + 513;
  int2* bpairs = (int2*)hA;  // alias: dead before cvt/gather ever touch hA

  const int NBK = (N + NPB - 1) >> 7;      // 391 for N=50000 (must be <= 512)
  const int EB  = (E + EPB - 1) / EPB;     // 391 edge-blocks

  // CSR build via bucket counting-sort (replaces atomic-scatter fill)
  zero_int_kernel<<<(NBK + 255) / 256, 256, 0, stream>>>(bcount, NBK);
  bkt_count_kernel<<<EB, 256, 0, stream>>>(dstv, bcount, E, NBK);
  bkt_scan_kernel<<<1, 512, 0, stream>>>(bcount, boff, bcur, rowp + N, E, NBK);
  bkt_fill_kernel<<<EB, 256, 0, stream>>>(srcv, dstv, bcur, bpairs, E, NBK);
  bkt_csr_kernel<<<NBK, 256, 0, stream>>>(bpairs, boff, rowp, csr, N, NBK);

  // combined bf16 GEMM weights + bf16 copy of initial h
  wb_kernel<<<(L * 256 * 128 + 255) / 256, 256, 0, stream>>>(wgt, wih, whh, WB,
                                                             L * 256 * 128);
  cvt_kernel<<<(N * DF + 255) / 256, 256, 0, stream>>>(x, hbf, N * DF);

  const float* hin = x;
  const int gruGrid = (N + 63) / 64;
  for (int i = 0; i < L; ++i) {
    gather_kernel<<<(N * DF + 255) / 256, 256, 0, stream>>>(hbf, rowp, csr, segHb, N);
    float* hout = (i == L - 1) ? out : ((i & 1) ? hB : hA);
    gru_mfma_kernel<<<gruGrid, 256, 0, stream>>>(segHb, hin, hbf, bih, bhh,
                                                 WB + (size_t)i * 256 * 128, hout, N);
    hin = hout;
  }
}

// Round 10
// 337.894 us; speedup vs baseline: 1.5725x; 1.0925x over previous
//
#include <hip/hip_runtime.h>
#include <hip/hip_bf16.h>
#include <math.h>

#define DF 64
#define NPB 128        // nodes per bucket (shift 7)
#define EPB 2048       // edges per block in bucket phases
#define DCAP 4608      // Phase-D per-bucket edge capacity (mean 2046, >50 sigma margin)

typedef __attribute__((ext_vector_type(8))) short short8v;   // 8 bf16 = 4 VGPRs
typedef __attribute__((ext_vector_type(4))) float f32x4;

__global__ __launch_bounds__(256) void zero_int_kernel(int* __restrict__ p, int n) {
  int i = blockIdx.x * 256 + threadIdx.x;
  if (i < n) p[i] = 0;
}

// Phase A: per-block LDS histogram of dst buckets -> global bucket counts
__global__ __launch_bounds__(256) void bkt_count_kernel(const int* __restrict__ dst,
                                                        int* __restrict__ bcount,
                                                        int e, int nbk) {
  __shared__ int cnt[512];
  for (int i = threadIdx.x; i < nbk; i += 256) cnt[i] = 0;
  __syncthreads();
  const int eb = blockIdx.x * EPB;
  const int ee = (eb + EPB < e) ? (eb + EPB) : e;
  for (int i = eb + threadIdx.x; i < ee; i += 256) atomicAdd(&cnt[dst[i] >> 7], 1);
  __syncthreads();
  for (int i = threadIdx.x; i < nbk; i += 256)
    if (cnt[i]) atomicAdd(&bcount[i], cnt[i]);
}

// Phase B: one-block exclusive scan of bucket counts (nbk <= 512); init cursors
__global__ __launch_bounds__(512) void bkt_scan_kernel(const int* __restrict__ bcount,
                                                       int* __restrict__ boff,
                                                       int* __restrict__ bcur,
                                                       int* __restrict__ rowp_last,
                                                       int e, int nbk) {
  __shared__ int a[512];
  const int t = threadIdx.x;
  int v = (t < nbk) ? bcount[t] : 0;
  a[t] = v;
  __syncthreads();
  for (int off = 1; off < 512; off <<= 1) {
    int add = (t >= off) ? a[t - off] : 0;
    __syncthreads();
    a[t] += add;
    __syncthreads();
  }
  int excl = a[t] - v;
  if (t < nbk) { boff[t] = excl; bcur[t] = excl; }
  if (t == nbk - 1) { boff[nbk] = excl + v; rowp_last[0] = e; }
}

// Phase C: bin edges into bucket segments as (src, dst&127) pairs.
__global__ __launch_bounds__(256) void bkt_fill_kernel(const int* __restrict__ src,
                                                       const int* __restrict__ dst,
                                                       int* __restrict__ bcur,
                                                       int2* __restrict__ bpairs,
                                                       int e, int nbk) {
  __shared__ int cnt[512];
  __shared__ int base[512];
  for (int i = threadIdx.x; i < nbk; i += 256) cnt[i] = 0;
  __syncthreads();
  const int eb = blockIdx.x * EPB;
  int s[8], d[8], r[8];
#pragma unroll
  for (int q = 0; q < 8; ++q) {
    int i = eb + q * 256 + threadIdx.x;
    bool ok = i < e;
    s[q] = ok ? src[i] : 0;
    d[q] = ok ? dst[i] : 0;
    r[q] = ok ? atomicAdd(&cnt[d[q] >> 7], 1) : 0;
  }
  __syncthreads();
  for (int i = threadIdx.x; i < nbk; i += 256)
    base[i] = cnt[i] ? atomicAdd(&bcur[i], cnt[i]) : 0;
  __syncthreads();
#pragma unroll
  for (int q = 0; q < 8; ++q) {
    int i = eb + q * 256 + threadIdx.x;
    if (i < e) {
      int b = d[q] >> 7;
      bpairs[base[b] + r[q]] = make_int2(s[q], d[q] & (NPB - 1));
    }
  }
}

// Phase D: one workgroup per bucket. Local hist -> scan -> LDS scatter;
// rowp and csr written fully coalesced.
__global__ __launch_bounds__(256) void bkt_csr_kernel(const int2* __restrict__ bpairs,
                                                      const int* __restrict__ boff,
                                                      int* __restrict__ rowp,
                                                      int* __restrict__ csr,
                                                      int n, int nbk) {
  __shared__ int cnt[NPB], cur[NPB], sa[NPB];
  __shared__ int lsrc[DCAP], ldst[DCAP], lcsr[DCAP];
  const int b = blockIdx.x;
  const int t = threadIdx.x;
  const int e0 = boff[b];
  int cnt_e = boff[b + 1] - e0;
  if (cnt_e > DCAP) cnt_e = DCAP;  // never triggers at this E/N; guards LDS OOB
  if (t < NPB) cnt[t] = 0;
  __syncthreads();
  for (int i = t; i < cnt_e; i += 256) {
    int2 p = bpairs[e0 + i];
    lsrc[i] = p.x;
    ldst[i] = p.y;
    atomicAdd(&cnt[p.y], 1);
  }
  __syncthreads();
  if (t < NPB) sa[t] = cnt[t];
  __syncthreads();
  for (int off = 1; off < NPB; off <<= 1) {
    int add = (t < NPB && t >= off) ? sa[t - off] : 0;
    __syncthreads();
    if (t < NPB) sa[t] += add;
    __syncthreads();
  }
  if (t < NPB) {
    int excl = sa[t] - cnt[t];
    cur[t] = excl;
    int node = b * NPB + t;
    if (node < n) rowp[node] = e0 + excl;
  }
  __syncthreads();
  for (int i = t; i < cnt_e; i += 256) {
    int p = atomicAdd(&cur[ldst[i]], 1);
    lcsr[p] = lsrc[i];
  }
  __syncthreads();
  for (int i = t; i < cnt_e; i += 256) csr[e0 + i] = lcsr[i];
}

// Combined GEMM weights, bf16, layout WB[l][c][k], c in 0..255, k in 0..127.
__global__ __launch_bounds__(256) void wb_kernel(const float* __restrict__ W,
                                                 const float* __restrict__ wih,
                                                 const float* __restrict__ whh,
                                                 __hip_bfloat16* __restrict__ WB,
                                                 int total) {
  int idx = blockIdx.x * 256 + threadIdx.x;
  if (idx >= total) return;
  int k = idx & 127;
  int c = (idx >> 7) & 255;
  int l = idx >> 15;
  int g = c >> 6;   // 0:r 1:z 2:i_n 3:h_n
  int f = c & 63;
  float v = 0.f;
  if (k < 64) {
    if (g != 3) {
      int crow = (g == 0) ? f : (g == 1) ? (64 + f) : (128 + f);
      const float* wr = W + ((size_t)l * 64 + k) * 64;
      const float* ir = wih + (size_t)crow * 64;
      float s = 0.f;
#pragma unroll
      for (int t2 = 0; t2 < 64; ++t2) s = fmaf(wr[t2], ir[t2], s);
      v = s;
    }
  } else {
    if (g != 2) {
      int crow = (g == 0) ? f : (g == 1) ? (64 + f) : (128 + f);
      v = whh[(size_t)crow * 64 + (k - 64)];
    }
  }
  WB[idx] = __float2bfloat16(v);
}

__global__ __launch_bounds__(256) void cvt_kernel(const float* __restrict__ x,
                                                  __hip_bfloat16* __restrict__ o, int n) {
  int i = blockIdx.x * 256 + threadIdx.x;
  if (i < n) o[i] = __float2bfloat16(x[i]);
}

// Vectorized gather: one wave per node; lane group g=lane>>4 handles every 4th
// edge; each lane loads 8B (4 features) -> one wave-instruction covers 4 edge
// rows (512B). 2-deep unroll = 8 rows in flight. Reduce via shfl_xor(16,32).
__global__ __launch_bounds__(256) void gather_kernel(const __hip_bfloat16* __restrict__ hb,
                                                     const int* __restrict__ rowp,
                                                     const int* __restrict__ csr,
                                                     __hip_bfloat16* __restrict__ segHb,
                                                     int n) {
  int w = (int)((blockIdx.x * 256 + threadIdx.x) >> 6);
  if (w >= n) return;
  const int lane = threadIdx.x & 63;
  const int g = lane >> 4;       // edge sub-stream 0..3
  const int fq = lane & 15;      // feature quad: features fq*4..fq*4+3
  const int beg = rowp[w], end = rowp[w + 1];
  float a0 = 0.f, a1 = 0.f, a2 = 0.f, a3 = 0.f;
  int e = beg + g;
  for (; e + 4 < end; e += 8) {
    int s0 = csr[e], s1 = csr[e + 4];
    uint2 v0 = *(const uint2*)(hb + (size_t)s0 * DF + fq * 4);
    uint2 v1 = *(const uint2*)(hb + (size_t)s1 * DF + fq * 4);
    a0 += __uint_as_float(v0.x << 16);
    a1 += __uint_as_float(v0.x & 0xffff0000u);
    a2 += __uint_as_float(v0.y << 16);
    a3 += __uint_as_float(v0.y & 0xffff0000u);
    a0 += __uint_as_float(v1.x << 16);
    a1 += __uint_as_float(v1.x & 0xffff0000u);
    a2 += __uint_as_float(v1.y << 16);
    a3 += __uint_as_float(v1.y & 0xffff0000u);
  }
  if (e < end) {
    int s0 = csr[e];
    uint2 v0 = *(const uint2*)(hb + (size_t)s0 * DF + fq * 4);
    a0 += __uint_as_float(v0.x << 16);
    a1 += __uint_as_float(v0.x & 0xffff0000u);
    a2 += __uint_as_float(v0.y << 16);
    a3 += __uint_as_float(v0.y & 0xffff0000u);
  }
  // combine the 4 edge sub-streams (lanes differing in bits 4-5)
  a0 += __shfl_xor(a0, 16); a1 += __shfl_xor(a1, 16);
  a2 += __shfl_xor(a2, 16); a3 += __shfl_xor(a3, 16);
  a0 += __shfl_xor(a0, 32); a1 += __shfl_xor(a1, 32);
  a2 += __shfl_xor(a2, 32); a3 += __shfl_xor(a3, 32);
  if (g == 0) {
    ushort2 p0 = make_ushort2(__bfloat16_as_ushort(__float2bfloat16(a0)),
                              __bfloat16_as_ushort(__float2bfloat16(a1)));
    ushort2 p1 = make_ushort2(__bfloat16_as_ushort(__float2bfloat16(a2)),
                              __bfloat16_as_ushort(__float2bfloat16(a3)));
    uint2 packed = make_uint2(((uint)p0.y << 16) | p0.x, ((uint)p1.y << 16) | p1.x);
    *(uint2*)(segHb + (size_t)w * DF + fq * 4) = packed;
  }
}

// swizzled LDS B-fragment read
__device__ __forceinline__ short8v ldB(const char* sB, int c, int chunk) {
  return *(const short8v*)(sB + c * 256 + ((chunk ^ (c & 15)) * 16));
}

#define MFMA(acc, a, b) acc = __builtin_amdgcn_mfma_f32_16x16x32_bf16(a, b, acc, 0, 0, 0)

// Fused GRU step via MFMA, bf16-only h state (hbf read+written in place).
// Final layer additionally writes fp32 out.
__global__ __launch_bounds__(256, 2) void gru_mfma_kernel(
    const __hip_bfloat16* __restrict__ segHb,
    __hip_bfloat16* __restrict__ hbf,  // state: read (A k>=64, hprev) and written
    const float* __restrict__ bih, const float* __restrict__ bhh,
    const __hip_bfloat16* __restrict__ WB, float* __restrict__ out,
    int writeOut, int n) {
  __shared__ __hip_bfloat16 sB[256 * 128];  // 64 KiB, chunk-XOR swizzled
#pragma unroll
  for (int i = 0; i < 16; ++i) {
    int idx = i * 256 + threadIdx.x;
    int c = idx >> 4, ch = idx & 15;
    short8v v = *(const short8v*)(WB + (size_t)c * 128 + ch * 8);
    *(short8v*)((char*)sB + c * 256 + ((ch ^ (c & 15)) * 16)) = v;
  }
  __syncthreads();

  const char* sBc = (const char*)sB;
  const int lane = threadIdx.x & 63;
  const int wid = threadIdx.x >> 6;
  const int row = lane & 15;     // node within 16-group (A); col within 16 (B/C)
  const int quad = lane >> 4;    // 0..3
  const int ch0 = quad, ch1 = 4 + quad, ch2 = 8 + quad, ch3 = 12 + quad;

  float bi_r[4], bi_z[4], bi_n[4], bh_r[4], bh_z[4], bh_n[4];
#pragma unroll
  for (int j = 0; j < 4; ++j) {
    int f = j * 16 + row;
    bi_r[j] = bih[f]; bi_z[j] = bih[64 + f]; bi_n[j] = bih[128 + f];
    bh_r[j] = bhh[f]; bh_z[j] = bhh[64 + f]; bh_n[j] = bhh[128 + f];
  }

  for (int nb0 = blockIdx.x * 64; nb0 < n; nb0 += gridDim.x * 64) {
    const int nb = nb0 + wid * 16;
    if (nb >= n) continue;
    const short8v a0 = *(const short8v*)(segHb + (size_t)(nb + row) * DF + quad * 8);
    const short8v a1 = *(const short8v*)(segHb + (size_t)(nb + row) * DF + 32 + quad * 8);
    const short8v a2 = *(const short8v*)(hbf + (size_t)(nb + row) * DF + quad * 8);
    const short8v a3 = *(const short8v*)(hbf + (size_t)(nb + row) * DF + 32 + quad * 8);

    f32x4 accR[4], accZ[4], accN[4], accH[4];
#pragma unroll
    for (int j = 0; j < 4; ++j) {
      accR[j] = (f32x4){0.f, 0.f, 0.f, 0.f};
      accZ[j] = (f32x4){0.f, 0.f, 0.f, 0.f};
      accN[j] = (f32x4){0.f, 0.f, 0.f, 0.f};
      accH[j] = (f32x4){0.f, 0.f, 0.f, 0.f};
    }
    // B-fragment column is PER-LANE: c = block + row
#pragma unroll
    for (int j = 0; j < 4; ++j) {
      MFMA(accR[j], a0, ldB(sBc, j * 16 + row, ch0));
      MFMA(accR[j], a1, ldB(sBc, j * 16 + row, ch1));
      MFMA(accR[j], a2, ldB(sBc, j * 16 + row, ch2));
      MFMA(accR[j], a3, ldB(sBc, j * 16 + row, ch3));
      MFMA(accZ[j], a0, ldB(sBc, 64 + j * 16 + row, ch0));
      MFMA(accZ[j], a1, ldB(sBc, 64 + j * 16 + row, ch1));
      MFMA(accZ[j], a2, ldB(sBc, 64 + j * 16 + row, ch2));
      MFMA(accZ[j], a3, ldB(sBc, 64 + j * 16 + row, ch3));
      MFMA(accN[j], a0, ldB(sBc, 128 + j * 16 + row, ch0));
      MFMA(accN[j], a1, ldB(sBc, 128 + j * 16 + row, ch1));
      MFMA(accH[j], a2, ldB(sBc, 192 + j * 16 + row, ch2));
      MFMA(accH[j], a3, ldB(sBc, 192 + j * 16 + row, ch3));
    }
    // epilogue: C layout col(lane&15)=feature-within-16, out-row = quad*4 + e = node
#pragma unroll
    for (int j = 0; j < 4; ++j) {
#pragma unroll
      for (int e = 0; e < 4; ++e) {
        const int node = nb + quad * 4 + e;
        const int f = j * 16 + row;
        const float hprev = __bfloat162float(hbf[(size_t)node * DF + f]);
        const float r = 1.f / (1.f + __expf(-(accR[j][e] + bi_r[j] + bh_r[j])));
        const float z = 1.f / (1.f + __expf(-(accZ[j][e] + bi_z[j] + bh_z[j])));
        const float nn = tanhf(accN[j][e] + bi_n[j] + r * (accH[j][e] + bh_n[j]));
        const float ho = fmaf(z, hprev - nn, nn);
        hbf[(size_t)node * DF + f] = __float2bfloat16(ho);
        if (writeOut) out[(size_t)node * DF + f] = ho;
      }
    }
  }
}

extern "C" void kernel_launch(void* const* d_in, const int* in_sizes, int n_in,
                              void* d_out, int out_size, void* d_ws, size_t ws_size,
                              hipStream_t stream) {
  const float* x   = (const float*)d_in[0];
  const int*   ei  = (const int*)d_in[1];
  const float* wgt = (const float*)d_in[2];
  const float* wih = (const float*)d_in[3];
  const float* whh = (const float*)d_in[4];
  const float* bih = (const float*)d_in[5];
  const float* bhh = (const float*)d_in[6];
  float* out = (float*)d_out;

  const int N = in_sizes[0] / DF;
  const int E = in_sizes[1] / 2;
  const int L = in_sizes[2] / (DF * DF);

  const int* srcv = ei;
  const int* dstv = ei + E;

  __hip_bfloat16* segHb = (__hip_bfloat16*)d_ws;
  __hip_bfloat16* hbf   = segHb + (size_t)N * DF;
  __hip_bfloat16* WB    = hbf + (size_t)N * DF;
  int* rowp   = (int*)(WB + (size_t)L * 256 * 128);
  int* csr    = rowp + (N + 1);
  int* bcount = csr + E;
  int* boff   = bcount + 512;
  int* bcur   = boff + 513;
  int2* bpairs = (int2*)(bcur + 512);

  const int NBK = (N + NPB - 1) >> 7;      // 391 for N=50000 (must be <= 512)
  const int EB  = (E + EPB - 1) / EPB;     // 391 edge-blocks

  // CSR build via bucket counting-sort
  zero_int_kernel<<<(NBK + 255) / 256, 256, 0, stream>>>(bcount, NBK);
  bkt_count_kernel<<<EB, 256, 0, stream>>>(dstv, bcount, E, NBK);
  bkt_scan_kernel<<<1, 512, 0, stream>>>(bcount, boff, bcur, rowp + N, E, NBK);
  bkt_fill_kernel<<<EB, 256, 0, stream>>>(srcv, dstv, bcur, bpairs, E, NBK);
  bkt_csr_kernel<<<NBK, 256, 0, stream>>>(bpairs, boff, rowp, csr, N, NBK);

  // combined bf16 GEMM weights + bf16 copy of initial h
  wb_kernel<<<(L * 256 * 128 + 255) / 256, 256, 0, stream>>>(wgt, wih, whh, WB,
                                                             L * 256 * 128);
  cvt_kernel<<<(N * DF + 255) / 256, 256, 0, stream>>>(x, hbf, N * DF);

  const int gruGrid = (N + 63) / 64;
  for (int i = 0; i < L; ++i) {
    gather_kernel<<<(N * DF + 255) / 256, 256, 0, stream>>>(hbf, rowp, csr, segHb, N);
    gru_mfma_kernel<<<gruGrid, 256, 0, stream>>>(segHb, hbf, bih, bhh,
                                                 WB + (size_t)i * 256 * 128, out,
                                                 (i == L - 1) ? 1 : 0, N);
  }
}